// Round 16
// baseline (28.509 us; speedup 1.0000x reference)
//
#include <hip/hip_runtime.h>

typedef __attribute__((ext_vector_type(8))) short bf16x8;
typedef __attribute__((ext_vector_type(4))) float f32x4;

constexpr int OBS  = 682;
constexpr int ACTN = 21;
constexpr int MB   = 8;           // rows per block

__device__ __forceinline__ unsigned short f2bf(float x) {
    unsigned u = __float_as_uint(x);
    return (unsigned short)((u + 0x7FFFu + ((u >> 16) & 1u)) >> 16);
}

constexpr int SC1S = 648;         // sc1 row stride (ushorts), padded for bank spread

__global__ __launch_bounds__(512, 6) void mfma_k(
    const float* __restrict__ obs,
    const float* __restrict__ c1w, const float* __restrict__ c1b,
    const float* __restrict__ c2w, const float* __restrict__ c2b,
    const float* __restrict__ f1w, const float* __restrict__ f1b,
    const float* __restrict__ f2w, const float* __restrict__ f2b,
    const float* __restrict__ f3w, const float* __restrict__ f3b,
    float* __restrict__ out)
{
    const int t = threadIdx.x;
    const int w = t >> 6, l = t & 63;
    const int q = l >> 4, l15 = l & 15;
    const int b8 = blockIdx.x * MB;

    __shared__ __align__(16) unsigned short sv[MB * 280];    // view bf16 [row][c*56+r*8+col]
    __shared__ __align__(16) unsigned short sc1[MB * SC1S];  // bf16 conv1 out [row][ic*20+pos]
    __shared__ __align__(16) unsigned short sc2[MB * 200];   // bf16 conv2 out [row][oc*6+pos]
    __shared__ __align__(16) float sfeat32[MB * 32];
    __shared__ __align__(16) float sx32[MB * 64];            // fp32 x; sh32 overlays
    __shared__ __align__(16) float sW[2624];                 // W2id[20][64] | W2act[21][64]
    __shared__ __align__(16) float sbias[224];               // c1b|c2b|f1b|f2b|f3b
    __shared__ int smeta[MB * 20];
    __shared__ __align__(16) unsigned short tap1[48];        // k -> c*56+kh*8+kw (0 for k>=45)
    __shared__ __align__(16) unsigned short tap2[288];       // k -> ic*20+kh*4+kw

    float* sh32 = sx32;               // overlay: sx32 dead after base (wave-row-local)

    // ================= phase 0: staging + tables + meta =================
    for (int e = t; e < MB * 210; e += 512) {                // view -> bf16 padded
        int row = e / 210, i2 = e - row * 210;
        int c = i2 / 42, rem = i2 - c * 42;
        int r3 = rem / 6, col = rem - r3 * 6;
        sv[row * 280 + c * 56 + r3 * 8 + col] = f2bf(obs[(long)(b8 + row) * OBS + i2]);
    }
    if (t < MB * 32) {                                       // feat -> fp32
        int row = t >> 5, j = t & 31;
        sfeat32[t] = obs[(long)(b8 + row) * OBS + 210 + j];
    }
    {                                                        // agent weights fp32 -> LDS
        const float4* srcw = (const float4*)(f2w + 96 * 64); // W2id|W2act 2624 floats
        float4* dw = (float4*)sW;
        if (t < 512) { dw[t] = srcw[t]; if (t < 144) dw[512 + t] = srcw[512 + t]; }
    }
    if (t < 224) {
        float v = 0.f;
        if (t < 32) v = c1b[t];
        else if (t < 64) v = c2b[t - 32];
        else if (t < 128) v = f1b[t - 64];
        else if (t < 192) v = f2b[t - 128];
        else if (t < 213) v = f3b[t - 192];
        sbias[t] = v;
    }
    if (t < 48) {
        int c = t / 9, rem = t - c * 9;
        tap1[t] = (t < 45) ? (unsigned short)(c * 56 + (rem / 3) * 8 + (rem % 3))
                           : (unsigned short)0;
    }
    if (t < 288) {
        int ic = t / 9, rem = t - ic * 9;
        tap2[t] = (unsigned short)(ic * 20 + (rem / 3) * 4 + (rem % 3));
    }
    if (t < MB * 20) {                                       // meta (exact fp32 from global)
        int row = t / 20, a = t - row * 20;
        const float* nb = obs + (long)(b8 + row) * OBS + 242 + a * 22;
        int id = (int)nb[0];
        int js = -1;
        #pragma unroll
        for (int j = 0; j < ACTN; ++j) {
            float av = nb[1 + j];
            js = (av != 0.f && js < 0) ? j : js;
        }
        int mode = (id < -1) ? 0 : ((id >= 0 && js < 0) ? 1 : 2);
        smeta[t] = ((id + 2) << 8) | (mode << 5) | (js + 1);
    }
    __syncthreads();

    // ========== phase 1: conv1 MFMA (M160 N32, 20 tiles), A from sv, B direct ==========
    {
        #pragma unroll
        for (int u = 0; u < 3; ++u) {
            int p = w + 8 * u;                  // tile = mt*2+nt
            if (p < 20) {
                int mt = p >> 1, nt = p & 1;
                int m = mt * 16 + l15;
                int brow = m / 20, pos = m - brow * 20;
                int base1 = brow * 280 + ((pos >> 2) << 3) + (pos & 3);
                const float* c1wn = c1w + (nt * 16 + l15) * 45;   // B column n
                f32x4 acc = {0.f, 0.f, 0.f, 0.f};
                {   // s = 0: k = 8q+j <= 31 < 45, no mask
                    const unsigned short* tp = &tap1[8 * q];
                    bf16x8 a, bb;
                    #pragma unroll
                    for (int j = 0; j < 8; ++j) {
                        a[j]  = (short)sv[base1 + tp[j]];
                        bb[j] = (short)f2bf(c1wn[8 * q + j]);
                    }
                    acc = __builtin_amdgcn_mfma_f32_16x16x32_bf16(a, bb, acc, 0, 0, 0);
                }
                {   // s = 1: k = 32+8q+j; valid iff k < 45 (q>=2 all zero)
                    bf16x8 a = {0, 0, 0, 0, 0, 0, 0, 0};
                    bf16x8 bb = {0, 0, 0, 0, 0, 0, 0, 0};
                    if (q < 2) {
                        const unsigned short* tp = &tap1[32 + 8 * q];
                        #pragma unroll
                        for (int j = 0; j < 8; ++j) {
                            int k = 32 + 8 * q + j;
                            unsigned short v = sv[base1 + tp[j]];
                            a[j]  = (k < 45) ? (short)v : (short)0;
                            bb[j] = (k < 45) ? (short)f2bf(c1wn[k]) : (short)0;
                        }
                    }
                    acc = __builtin_amdgcn_mfma_f32_16x16x32_bf16(a, bb, acc, 0, 0, 0);
                }
                int oc = nt * 16 + l15;
                float bias = sbias[oc];
                #pragma unroll
                for (int r = 0; r < 4; ++r) {
                    int mm = mt * 16 + 4 * q + r;
                    int row = mm / 20, ps = mm - row * 20;
                    sc1[row * SC1S + oc * 20 + ps] = f2bf(fmaxf(acc[r] + bias, 0.f));
                }
            }
        }
    }
    __syncthreads();

    // ========== phase 2: conv2 MFMA (M48 N32), A from sc1, B direct ==========
    if (w < 6) {
        int mt = w >> 1, nt = w & 1;
        int m = mt * 16 + l15;
        int rowm = m / 6, posm = m - rowm * 6;
        int base2 = rowm * SC1S + ((posm >> 1) << 2) + (posm & 1);
        const float* c2wn = c2w + (nt * 16 + l15) * 288 + 8 * q;  // B column n, k-offset 8q
        f32x4 acc = {0.f, 0.f, 0.f, 0.f};
        #pragma unroll
        for (int s = 0; s < 9; ++s) {
            const unsigned short* tp = &tap2[32 * s + 8 * q];
            bf16x8 a, bb;
            #pragma unroll
            for (int j = 0; j < 8; ++j) {
                a[j]  = (short)sc1[base2 + tp[j]];
                bb[j] = (short)f2bf(c2wn[32 * s + j]);
            }
            acc = __builtin_amdgcn_mfma_f32_16x16x32_bf16(a, bb, acc, 0, 0, 0);
        }
        int oc = nt * 16 + l15;
        float bias = sbias[32 + oc];
        #pragma unroll
        for (int r = 0; r < 4; ++r) {
            int mm = mt * 16 + 4 * q + r;
            int row = mm / 6, ps = mm - row * 6;
            sc2[row * 200 + oc * 6 + ps] = f2bf(fmaxf(acc[r] + bias, 0.f));
        }
    }
    __syncthreads();

    // ========== phase 3: fc1 MFMA (M16(8 valid) N64 K192), B direct ==========
    if (w < 4) {
        int nt = w;
        const float* f1wn = f1w + (nt * 16 + l15);               // B column n (stride 64)
        f32x4 acc = {0.f, 0.f, 0.f, 0.f};
        #pragma unroll
        for (int s = 0; s < 6; ++s) {
            bf16x8 a = *(const bf16x8*)&sc2[l15 * 200 + 32 * s + 8 * q];
            bf16x8 bb;
            #pragma unroll
            for (int j = 0; j < 8; ++j)
                bb[j] = (short)f2bf(f1wn[(32 * s + 8 * q + j) * 64]);
            acc = __builtin_amdgcn_mfma_f32_16x16x32_bf16(a, bb, acc, 0, 0, 0);
        }
        int h = nt * 16 + l15;
        float bias = sbias[64 + h];
        #pragma unroll
        for (int r = 0; r < 4; ++r) {
            int row = 4 * q + r;
            if (row < MB) sx32[row * 64 + h] = fmaxf(acc[r] + bias, 0.f);
        }
    }
    __syncthreads();

    // ============ phase 4: base + agents + fc3, wave-row-local (row = w) ============
    float cnt;
    {
        const int row = w;
        // base (fp32, exact); W2x/W2f read directly from global (L2-resident)
        float a0 = sbias[128 + l], a1 = 0.f;
        #pragma unroll 4
        for (int k = 0; k < 64; k += 2) {
            a0 = fmaf(sx32[row * 64 + k],     f2w[(k    ) * 64 + l], a0);
            a1 = fmaf(sx32[row * 64 + k + 1], f2w[(k + 1) * 64 + l], a1);
        }
        #pragma unroll 4
        for (int k = 0; k < 32; k += 2) {
            a0 = fmaf(sfeat32[row * 32 + k],     f2w[(64 + k    ) * 64 + l], a0);
            a1 = fmaf(sfeat32[row * 32 + k + 1], f2w[(64 + k + 1) * 64 + l], a1);
        }
        const float base_l = a0 + a1;
        // agents (fp32, exact logic; W2id/W2act from LDS)
        float hacc = 0.f;
        cnt = 0.f;
        for (int a = 0; a < 20; ++a) {
            int m = smeta[row * 20 + a];
            int mode = (m >> 5) & 3;
            if (mode == 0) continue;
            int id = (m >> 8) - 2;
            int js = (m & 31) - 1;
            float u = base_l + ((id >= 0) ? sW[id * 64 + l] : 0.f);
            if (mode == 1) {                 // expand: sum_j relu(u + W2act[j])
                float h0 = 0.f, h1 = 0.f, h2 = 0.f;
                #pragma unroll
                for (int j = 0; j < ACTN; j += 3) {
                    h0 += fmaxf(u + sW[1280 + (j    ) * 64 + l], 0.f);
                    h1 += fmaxf(u + sW[1280 + (j + 1) * 64 + l], 0.f);
                    h2 += fmaxf(u + sW[1280 + (j + 2) * 64 + l], 0.f);
                }
                hacc += (h0 + h1) + h2;
                cnt  += 21.f;
            } else {
                float ar = (js >= 0) ? sW[1280 + js * 64 + l] : 0.f;
                hacc += fmaxf(u + ar, 0.f);
                cnt  += 1.f;
            }
        }
        sh32[row * 64 + l] = hacc;           // overlay over sx32 (own row, read done)
    }
    // no barrier: fc3 reads only row w, written by this wave

    if (l < ACTN) {
        float qv = cnt * sbias[192 + l];     // cnt is wave-uniform, in register
        float q1 = 0.f;
        #pragma unroll 4
        for (int h = 0; h < 64; h += 2) {
            qv = fmaf(sh32[w * 64 + h],     f3w[(h    ) * 21 + l], qv);
            q1 = fmaf(sh32[w * 64 + h + 1], f3w[(h + 1) * 21 + l], q1);
        }
        out[(long)(b8 + w) * 21 + l] = qv + q1;
    }
}

// ================= fallback: R6 structure, raw weights =================
__device__ __forceinline__ float comp4(float4 v, int i) {
    return (i == 0) ? v.x : (i == 1) ? v.y : (i == 2) ? v.z : v.w;
}

constexpr int S_V = 0, S_OBS = 280, S_C1 = 968, S_PART = 1608, S_C2 = 1992,
              S_X = 2184, S_H = 2248, S_TOT = 2312;

__global__ __launch_bounds__(64, 4) void fallback_k(
    const float* __restrict__ obs,
    const float* __restrict__ c1w, const float* __restrict__ c1b,
    const float* __restrict__ c2w, const float* __restrict__ c2b,
    const float* __restrict__ f1w, const float* __restrict__ f1b,
    const float* __restrict__ f2w, const float* __restrict__ f2b,
    const float* __restrict__ f3w, const float* __restrict__ f3b,
    float* __restrict__ out)
{
    const int b = blockIdx.x, t = threadIdx.x;
    __shared__ __align__(16) float sb[S_TOT];
    __shared__ int s_meta[20];
    {
        const float* orow = obs + (long)b * OBS;
        #pragma unroll
        for (int k = 0; k < 4; ++k) {
            int i = t + k * 64;
            if (i < 210) {
                int c = i / 42, rem = i - 42 * c, r = rem / 6, col = rem - 6 * r;
                sb[S_V + c * 56 + r * 8 + col] = orow[i];
            }
        }
        #pragma unroll
        for (int k = 0; k < 8; ++k) {
            int i = 210 + t + k * 64;
            if (i < OBS) sb[S_OBS + i] = orow[i];
        }
    }
    __syncthreads();
    if (t < 20) {
        const float* nb = &sb[S_OBS + 242 + t * 22];
        int id = (int)nb[0], js = -1;
        #pragma unroll
        for (int j = 0; j < ACTN; ++j) {
            float av = nb[1 + j];
            js = (av != 0.f && js < 0) ? j : js;
        }
        int mode = (id < -1) ? 0 : ((id >= 0 && js < 0) ? 1 : 2);
        s_meta[t] = ((id + 2) << 8) | (mode << 5) | (js + 1);
    }
    {
        const int oc = t & 31, s = t >> 5;
        float acc[12];
        #pragma unroll
        for (int i = 0; i < 12; ++i) acc[i] = 0.f;
        #pragma unroll
        for (int c = 0; c < 5; ++c) {
            float wv[9];
            #pragma unroll
            for (int k = 0; k < 9; ++k) wv[k] = c1w[oc * 45 + c * 9 + k];
            #pragma unroll
            for (int rr = 0; rr < 5; ++rr) {
                const float* rowp = &sb[S_V + c * 56 + (2 * s + rr) * 8];
                float4 v0 = *(const float4*)rowp;
                float2 v1 = *(const float2*)(rowp + 4);
                float c0 = v0.x, c1 = v0.y, c2 = v0.z, c3 = v0.w, c4 = v1.x, c5 = v1.y;
                #pragma unroll
                for (int kh = 0; kh < 3; ++kh) {
                    int ohl = rr - kh;
                    if (ohl < 0 || ohl > 2) continue;
                    acc[ohl*4+0] = fmaf(c0, wv[kh*3+0], acc[ohl*4+0]);
                    acc[ohl*4+0] = fmaf(c1, wv[kh*3+1], acc[ohl*4+0]);
                    acc[ohl*4+0] = fmaf(c2, wv[kh*3+2], acc[ohl*4+0]);
                    acc[ohl*4+1] = fmaf(c1, wv[kh*3+0], acc[ohl*4+1]);
                    acc[ohl*4+1] = fmaf(c2, wv[kh*3+1], acc[ohl*4+1]);
                    acc[ohl*4+1] = fmaf(c3, wv[kh*3+2], acc[ohl*4+1]);
                    acc[ohl*4+2] = fmaf(c2, wv[kh*3+0], acc[ohl*4+2]);
                    acc[ohl*4+2] = fmaf(c3, wv[kh*3+1], acc[ohl*4+2]);
                    acc[ohl*4+2] = fmaf(c4, wv[kh*3+2], acc[ohl*4+2]);
                    acc[ohl*4+3] = fmaf(c3, wv[kh*3+0], acc[ohl*4+3]);
                    acc[ohl*4+3] = fmaf(c4, wv[kh*3+1], acc[ohl*4+3]);
                    acc[ohl*4+3] = fmaf(c5, wv[kh*3+2], acc[ohl*4+3]);
                }
            }
        }
        float bias = c1b[oc];
        #pragma unroll
        for (int ohl = 0; ohl < 3; ++ohl) {
            int oh = 2 * s + ohl;
            float4 o4 = make_float4(fmaxf(acc[ohl*4+0] + bias, 0.f), fmaxf(acc[ohl*4+1] + bias, 0.f),
                                    fmaxf(acc[ohl*4+2] + bias, 0.f), fmaxf(acc[ohl*4+3] + bias, 0.f));
            *(float4*)&sb[S_C1 + oc * 20 + oh * 4] = o4;
        }
    }
    __syncthreads();
    {
        const int oc = t & 31, half = t >> 5;
        float a0=0,a1=0,a2=0,a3=0,a4=0,a5=0;
        #pragma unroll 4
        for (int icc = 0; icc < 16; ++icc) {
            const int ic = half * 16 + icc;
            const float4* rp = (const float4*)&sb[S_C1 + ic * 20];
            float4 r0 = rp[0], r1 = rp[1], r2 = rp[2], r3 = rp[3], r4 = rp[4];
            float wv[9];
            #pragma unroll
            for (int k = 0; k < 9; ++k) wv[k] = c2w[oc * 288 + ic * 9 + k];
            #pragma unroll
            for (int kh = 0; kh < 3; ++kh) {
                float4 ra = (kh == 0) ? r0 : (kh == 1) ? r1 : r2;
                float4 rb = (kh == 0) ? r1 : (kh == 1) ? r2 : r3;
                float4 rc = (kh == 0) ? r2 : (kh == 1) ? r3 : r4;
                #pragma unroll
                for (int kw = 0; kw < 3; ++kw) {
                    float ww = wv[kh * 3 + kw];
                    a0 = fmaf(comp4(ra, kw),     ww, a0);
                    a1 = fmaf(comp4(ra, kw + 1), ww, a1);
                    a2 = fmaf(comp4(rb, kw),     ww, a2);
                    a3 = fmaf(comp4(rb, kw + 1), ww, a3);
                    a4 = fmaf(comp4(rc, kw),     ww, a4);
                    a5 = fmaf(comp4(rc, kw + 1), ww, a5);
                }
            }
        }
        float* pp = &sb[S_PART + (half * 32 + oc) * 6];
        pp[0]=a0; pp[1]=a1; pp[2]=a2; pp[3]=a3; pp[4]=a4; pp[5]=a5;
    }
    __syncthreads();
    if (t < 32) {
        float bias = c2b[t];
        #pragma unroll
        for (int p = 0; p < 6; ++p)
            sb[S_C2 + t * 6 + p] = fmaxf(sb[S_PART + t * 6 + p] + sb[S_PART + (32 + t) * 6 + p] + bias, 0.f);
    }
    __syncthreads();
    {
        float a0 = f1b[t], a1 = 0.f;
        const float4* xp = (const float4*)&sb[S_C2];
        #pragma unroll 4
        for (int kq = 0; kq < 48; ++kq) {
            float4 x = xp[kq];
            a0 = fmaf(x.x, f1w[(4*kq+0)*64+t], a0);
            a1 = fmaf(x.y, f1w[(4*kq+1)*64+t], a1);
            a0 = fmaf(x.z, f1w[(4*kq+2)*64+t], a0);
            a1 = fmaf(x.w, f1w[(4*kq+3)*64+t], a1);
        }
        sb[S_X + t] = fmaxf(a0 + a1, 0.f);
    }
    __syncthreads();
    float base_t;
    {
        float a0 = f2b[t], a1 = 0.f;
        const float4* xp = (const float4*)&sb[S_X];
        #pragma unroll 4
        for (int kq = 0; kq < 16; ++kq) {
            float4 x = xp[kq];
            a0 = fmaf(x.x, f2w[(4*kq+0)*64+t], a0);
            a1 = fmaf(x.y, f2w[(4*kq+1)*64+t], a1);
            a0 = fmaf(x.z, f2w[(4*kq+2)*64+t], a0);
            a1 = fmaf(x.w, f2w[(4*kq+3)*64+t], a1);
        }
        const float2* fp = (const float2*)&sb[S_OBS + 210];
        #pragma unroll 4
        for (int i2 = 0; i2 < 16; ++i2) {
            float2 v = fp[i2];
            a0 = fmaf(v.x, f2w[(64 + i2*2+0)*64+t], a0);
            a1 = fmaf(v.y, f2w[(64 + i2*2+1)*64+t], a1);
        }
        base_t = a0 + a1;
    }
    const float* W2id = f2w + 96 * 64;
    const float* W2act = f2w + 116 * 64;
    float hacc = 0.f, cnt = 0.f;
    for (int a = 0; a < 20; ++a) {
        int m = s_meta[a];
        int mode = (m >> 5) & 3;
        if (mode == 0) continue;
        int id = (m >> 8) - 2, js = (m & 31) - 1;
        float u = base_t + ((id >= 0) ? W2id[id * 64 + t] : 0.f);
        if (mode == 1) {
            float h0=0,h1=0,h2=0;
            #pragma unroll
            for (int j = 0; j < ACTN; j += 3) {
                h0 += fmaxf(u + W2act[(j    )*64+t], 0.f);
                h1 += fmaxf(u + W2act[(j + 1)*64+t], 0.f);
                h2 += fmaxf(u + W2act[(j + 2)*64+t], 0.f);
            }
            hacc += (h0 + h1) + h2; cnt += 21.f;
        } else {
            float ar = (js >= 0) ? W2act[js * 64 + t] : 0.f;
            hacc += fmaxf(u + ar, 0.f); cnt += 1.f;
        }
    }
    sb[S_H + t] = hacc;
    __syncthreads();
    if (t < ACTN) {
        float q0 = cnt * f3b[t], q1 = 0.f;
        const float4* hp = (const float4*)&sb[S_H];
        #pragma unroll 4
        for (int h4 = 0; h4 < 16; ++h4) {
            float4 v = hp[h4];
            q0 = fmaf(v.x, f3w[(h4*4+0)*21+t], q0);
            q1 = fmaf(v.y, f3w[(h4*4+1)*21+t], q1);
            q0 = fmaf(v.z, f3w[(h4*4+2)*21+t], q0);
            q1 = fmaf(v.w, f3w[(h4*4+3)*21+t], q1);
        }
        out[b * 21 + t] = q0 + q1;
    }
}

extern "C" void kernel_launch(void* const* d_in, const int* in_sizes, int n_in,
                              void* d_out, int out_size, void* d_ws, size_t ws_size,
                              hipStream_t stream) {
    const float* obs = (const float*)d_in[0];
    const float* c1w = (const float*)d_in[1];
    const float* c1b = (const float*)d_in[2];
    const float* c2w = (const float*)d_in[3];
    const float* c2b = (const float*)d_in[4];
    const float* f1w = (const float*)d_in[5];
    const float* f1b = (const float*)d_in[6];
    const float* f2w = (const float*)d_in[7];
    const float* f2b = (const float*)d_in[8];
    const float* f3w = (const float*)d_in[9];
    const float* f3b = (const float*)d_in[10];
    float* o = (float*)d_out;
    const int B = in_sizes[0] / OBS;

    if ((B % MB) == 0) {
        mfma_k<<<B / MB, 512, 0, stream>>>(obs, c1w, c1b, c2w, c2b, f1w, f1b,
                                           f2w, f2b, f3w, f3b, o);
    } else {
        fallback_k<<<B, 64, 0, stream>>>(obs, c1w, c1b, c2w, c2b, f1w, f1b,
                                         f2w, f2b, f3w, f3b, o);
    }
}

// Round 17
// 26.303 us; speedup vs baseline: 1.0839x; 1.0839x over previous
//
#include <hip/hip_runtime.h>

typedef __attribute__((ext_vector_type(8))) short bf16x8;
typedef __attribute__((ext_vector_type(4))) float f32x4;

constexpr int OBS  = 682;
constexpr int ACTN = 21;
constexpr int MB   = 8;           // rows per block

// ---- ws (ushort units): bf16 B-fragments, 512 ushorts per 16x16x32 frag ----
constexpr int WS_C1U  = 0;        // conv1: K=64(pad from 45), N=32 -> 2s x 2nt = 4 frags
constexpr int WS_C2U  = 2048;     // conv2: K=288, N=32 -> 9s x 2nt = 18 frags
constexpr int WS_F1U  = 11264;    // fc1:   K=192, N=64 -> 6s x 4nt = 24 frags
constexpr int WS_TOTU = 23552;    // 46 frags

__device__ __forceinline__ unsigned short f2bf(float x) {
    unsigned u = __float_as_uint(x);
    return (unsigned short)((u + 0x7FFFu + ((u >> 16) & 1u)) >> 16);
}

__global__ void repack_b(const float* __restrict__ c1w, const float* __restrict__ c2w,
                         const float* __restrict__ f1w, unsigned short* __restrict__ wsu) {
    int i = blockIdx.x * 256 + threadIdx.x;
    if (i >= WS_TOTU) return;
    int frag = i >> 9, within = i & 511;
    int l = within >> 3, j = within & 7;
    int q = l >> 4, l15 = l & 15;
    float v = 0.f;
    if (frag < 4) {                          // conv1 B[k<45 pad64][oc32]
        int s = frag >> 1, nt = frag & 1;
        int k = 32 * s + 8 * q + j, n = 16 * nt + l15;
        if (k < 45) v = c1w[n * 45 + k];
    } else if (frag < 22) {                  // conv2 B[288][32]
        int f = frag - 4, s = f >> 1, nt = f & 1;
        int k = 32 * s + 8 * q + j, n = 16 * nt + l15;
        v = c2w[n * 288 + k];
    } else {                                 // fc1 B[192][64]
        int f = frag - 22, s = f >> 2, nt = f & 3;
        int k = 32 * s + 8 * q + j, n = 16 * nt + l15;
        v = f1w[k * 64 + n];
    }
    wsu[i] = f2bf(v);
}

constexpr int SC1S = 648;         // sc1 row stride (ushorts), padded for bank spread

__global__ __launch_bounds__(512, 6) void mfma_k(
    const float* __restrict__ obs,
    const float* __restrict__ c1b, const float* __restrict__ c2b,
    const float* __restrict__ f1b, const float* __restrict__ f2w,
    const float* __restrict__ f2b, const float* __restrict__ f3w,
    const float* __restrict__ f3b,
    const unsigned short* __restrict__ wsu,
    float* __restrict__ out)
{
    const int t = threadIdx.x;
    const int w = t >> 6, l = t & 63;
    const int q = l >> 4, l15 = l & 15;
    const int b8 = blockIdx.x * MB;

    __shared__ __align__(16) unsigned short sv[MB * 280];    // view bf16 [row][c*56+r*8+col]
    __shared__ __align__(16) unsigned short sc1[MB * SC1S];  // bf16 conv1 out [row][ic*20+pos]
    __shared__ __align__(16) unsigned short sc2[MB * 200];   // bf16 conv2 out [row][oc*6+pos]
    __shared__ __align__(16) float sfeat32[MB * 32];
    __shared__ __align__(16) float sx32[MB * 64];            // fp32 x; sh32 overlays
    __shared__ __align__(16) float sW[2624];                 // W2id[20][64] | W2act[21][64]
    __shared__ __align__(16) float sbias[224];               // c1b|c2b|f1b|f2b|f3b
    __shared__ int smeta[MB * 20];
    __shared__ __align__(16) unsigned short tap1[48];        // k -> c*56+kh*8+kw (0 for k>=45)
    __shared__ __align__(16) unsigned short tap2[288];       // k -> ic*20+kh*4+kw

    float* sh32 = sx32;               // overlay: sx32 dead after base (wave-row-local)

    // ========== phase 0: view staging + small tables only ==========
    for (int e = t; e < MB * 210; e += 512) {                // view -> bf16 padded
        int row = e / 210, i2 = e - row * 210;
        int c = i2 / 42, rem = i2 - c * 42;
        int r3 = rem / 6, col = rem - r3 * 6;
        sv[row * 280 + c * 56 + r3 * 8 + col] = f2bf(obs[(long)(b8 + row) * OBS + i2]);
    }
    if (t < 224) {
        float v = 0.f;
        if (t < 32) v = c1b[t];
        else if (t < 64) v = c2b[t - 32];
        else if (t < 128) v = f1b[t - 64];
        else if (t < 192) v = f2b[t - 128];
        else if (t < 213) v = f3b[t - 192];
        sbias[t] = v;
    }
    if (t < 48) {
        int c = t / 9, rem = t - c * 9;
        tap1[t] = (t < 45) ? (unsigned short)(c * 56 + (rem / 3) * 8 + (rem % 3))
                           : (unsigned short)0;
    }
    if (t < 288) {
        int ic = t / 9, rem = t - ic * 9;
        tap2[t] = (unsigned short)(ic * 20 + (rem / 3) * 4 + (rem % 3));
    }
    __syncthreads();

    // ========== phase 1: conv1 MFMA (M160 N32, 20 tiles), A gathered from sv ==========
    {
        #pragma unroll
        for (int u = 0; u < 3; ++u) {
            int p = w + 8 * u;                  // tile = mt*2+nt
            if (p < 20) {
                int mt = p >> 1, nt = p & 1;
                int m = mt * 16 + l15;
                int brow = m / 20, pos = m - brow * 20;
                int base1 = brow * 280 + ((pos >> 2) << 3) + (pos & 3);
                f32x4 acc = {0.f, 0.f, 0.f, 0.f};
                {   // s = 0: k = 8q+j <= 31 < 45, no mask
                    const unsigned short* tp = &tap1[8 * q];
                    bf16x8 a;
                    #pragma unroll
                    for (int j = 0; j < 8; ++j)
                        a[j] = (short)sv[base1 + tp[j]];
                    bf16x8 bb = *(const bf16x8*)&wsu[WS_C1U + (0 + nt) * 512 + l * 8];
                    acc = __builtin_amdgcn_mfma_f32_16x16x32_bf16(a, bb, acc, 0, 0, 0);
                }
                {   // s = 1: k = 32+8q+j; valid iff 8q+j < 13 (q>=2 all zero)
                    bf16x8 a = {0, 0, 0, 0, 0, 0, 0, 0};
                    if (q < 2) {
                        const unsigned short* tp = &tap1[32 + 8 * q];
                        #pragma unroll
                        for (int j = 0; j < 8; ++j) {
                            unsigned short v = sv[base1 + tp[j]];
                            a[j] = (8 * q + j < 13) ? (short)v : (short)0;
                        }
                    }
                    bf16x8 bb = *(const bf16x8*)&wsu[WS_C1U + (2 + nt) * 512 + l * 8];
                    acc = __builtin_amdgcn_mfma_f32_16x16x32_bf16(a, bb, acc, 0, 0, 0);
                }
                int oc = nt * 16 + l15;
                float bias = sbias[oc];
                #pragma unroll
                for (int r = 0; r < 4; ++r) {
                    int mm = mt * 16 + 4 * q + r;
                    int row = mm / 20, ps = mm - row * 20;
                    sc1[row * SC1S + oc * 20 + ps] = f2bf(fmaxf(acc[r] + bias, 0.f));
                }
            }
        }
    }
    __syncthreads();

    // ========== phase 2: conv2 MFMA (waves 0-5) ∥ sW staging (waves 6-7) ==========
    if (w < 6) {
        int mt = w >> 1, nt = w & 1;
        int m = mt * 16 + l15;
        int rowm = m / 6, posm = m - rowm * 6;
        int base2 = rowm * SC1S + ((posm >> 1) << 2) + (posm & 1);
        f32x4 acc = {0.f, 0.f, 0.f, 0.f};
        #pragma unroll
        for (int s = 0; s < 9; ++s) {
            const unsigned short* tp = &tap2[32 * s + 8 * q];
            bf16x8 a;
            #pragma unroll
            for (int j = 0; j < 8; ++j)
                a[j] = (short)sc1[base2 + tp[j]];
            bf16x8 bb = *(const bf16x8*)&wsu[WS_C2U + (s * 2 + nt) * 512 + l * 8];
            acc = __builtin_amdgcn_mfma_f32_16x16x32_bf16(a, bb, acc, 0, 0, 0);
        }
        int oc = nt * 16 + l15;
        float bias = sbias[32 + oc];
        #pragma unroll
        for (int r = 0; r < 4; ++r) {
            int mm = mt * 16 + 4 * q + r;
            int row = mm / 6, ps = mm - row * 6;
            sc2[row * 200 + oc * 6 + ps] = f2bf(fmaxf(acc[r] + bias, 0.f));
        }
    } else {
        // waves 6-7: stage agent weights (W2id|W2act, 2624 floats) for phase 4
        const float4* srcw = (const float4*)(f2w + 96 * 64);
        float4* dw = (float4*)sW;
        int base = t - 384;                      // 0..127
        #pragma unroll
        for (int kk = 0; kk < 6; ++kk) {
            int i = base + kk * 128;
            if (i < 656) dw[i] = srcw[i];
        }
    }
    __syncthreads();

    // ========== phase 3: fc1 MFMA (waves 0-3) ∥ feat+meta staging (waves 4-7) ==========
    if (w < 4) {
        int nt = w;
        f32x4 acc = {0.f, 0.f, 0.f, 0.f};
        #pragma unroll
        for (int s = 0; s < 6; ++s) {
            bf16x8 a = *(const bf16x8*)&sc2[l15 * 200 + 32 * s + 8 * q];
            bf16x8 bb = *(const bf16x8*)&wsu[WS_F1U + (s * 4 + nt) * 512 + l * 8];
            acc = __builtin_amdgcn_mfma_f32_16x16x32_bf16(a, bb, acc, 0, 0, 0);
        }
        int h = nt * 16 + l15;
        float bias = sbias[64 + h];
        #pragma unroll
        for (int r = 0; r < 4; ++r) {
            int row = 4 * q + r;
            if (row < MB) sx32[row * 64 + h] = fmaxf(acc[r] + bias, 0.f);
        }
    } else {
        int base = t - 256;                      // 0..255
        {                                        // feat -> fp32 (256 elems)
            int row = base >> 5, j = base & 31;
            sfeat32[row * 32 + j] = obs[(long)(b8 + row) * OBS + 210 + j];
        }
        if (base < MB * 20) {                    // meta (exact fp32 from global)
            int row = base / 20, a = base - row * 20;
            const float* nb = obs + (long)(b8 + row) * OBS + 242 + a * 22;
            int id = (int)nb[0];
            int js = -1;
            #pragma unroll
            for (int j = 0; j < ACTN; ++j) {
                float av = nb[1 + j];
                js = (av != 0.f && js < 0) ? j : js;
            }
            int mode = (id < -1) ? 0 : ((id >= 0 && js < 0) ? 1 : 2);
            smeta[base] = ((id + 2) << 8) | (mode << 5) | (js + 1);
        }
    }
    __syncthreads();

    // ============ phase 4: base + agents + fc3, wave-row-local (row = w) ============
    float cnt;
    {
        const int row = w;
        // base (fp32, exact); W2x/W2f read directly from global (L2-resident)
        float a0 = sbias[128 + l], a1 = 0.f;
        #pragma unroll 4
        for (int k = 0; k < 64; k += 2) {
            a0 = fmaf(sx32[row * 64 + k],     f2w[(k    ) * 64 + l], a0);
            a1 = fmaf(sx32[row * 64 + k + 1], f2w[(k + 1) * 64 + l], a1);
        }
        #pragma unroll 4
        for (int k = 0; k < 32; k += 2) {
            a0 = fmaf(sfeat32[row * 32 + k],     f2w[(64 + k    ) * 64 + l], a0);
            a1 = fmaf(sfeat32[row * 32 + k + 1], f2w[(64 + k + 1) * 64 + l], a1);
        }
        const float base_l = a0 + a1;
        // agents (fp32, exact logic; W2id/W2act from LDS)
        float hacc = 0.f;
        cnt = 0.f;
        for (int a = 0; a < 20; ++a) {
            int m = smeta[row * 20 + a];
            int mode = (m >> 5) & 3;
            if (mode == 0) continue;
            int id = (m >> 8) - 2;
            int js = (m & 31) - 1;
            float u = base_l + ((id >= 0) ? sW[id * 64 + l] : 0.f);
            if (mode == 1) {                 // expand: sum_j relu(u + W2act[j])
                float h0 = 0.f, h1 = 0.f, h2 = 0.f;
                #pragma unroll
                for (int j = 0; j < ACTN; j += 3) {
                    h0 += fmaxf(u + sW[1280 + (j    ) * 64 + l], 0.f);
                    h1 += fmaxf(u + sW[1280 + (j + 1) * 64 + l], 0.f);
                    h2 += fmaxf(u + sW[1280 + (j + 2) * 64 + l], 0.f);
                }
                hacc += (h0 + h1) + h2;
                cnt  += 21.f;
            } else {
                float ar = (js >= 0) ? sW[1280 + js * 64 + l] : 0.f;
                hacc += fmaxf(u + ar, 0.f);
                cnt  += 1.f;
            }
        }
        sh32[row * 64 + l] = hacc;           // overlay over sx32 (own row, read done)
    }
    // no barrier: fc3 reads only row w, written by this wave

    if (l < ACTN) {
        float qv = cnt * sbias[192 + l];     // cnt is wave-uniform, in register
        float q1 = 0.f;
        #pragma unroll 4
        for (int h = 0; h < 64; h += 2) {
            qv = fmaf(sh32[w * 64 + h],     f3w[(h    ) * 21 + l], qv);
            q1 = fmaf(sh32[w * 64 + h + 1], f3w[(h + 1) * 21 + l], q1);
        }
        out[(long)(b8 + w) * 21 + l] = qv + q1;
    }
}

// ================= fallback: R6 structure, raw weights (no ws) =================
__device__ __forceinline__ float comp4(float4 v, int i) {
    return (i == 0) ? v.x : (i == 1) ? v.y : (i == 2) ? v.z : v.w;
}

constexpr int S_V = 0, S_OBS = 280, S_C1 = 968, S_PART = 1608, S_C2 = 1992,
              S_X = 2184, S_H = 2248, S_TOT = 2312;

__global__ __launch_bounds__(64, 4) void fallback_k(
    const float* __restrict__ obs,
    const float* __restrict__ c1w, const float* __restrict__ c1b,
    const float* __restrict__ c2w, const float* __restrict__ c2b,
    const float* __restrict__ f1w, const float* __restrict__ f1b,
    const float* __restrict__ f2w, const float* __restrict__ f2b,
    const float* __restrict__ f3w, const float* __restrict__ f3b,
    float* __restrict__ out)
{
    const int b = blockIdx.x, t = threadIdx.x;
    __shared__ __align__(16) float sb[S_TOT];
    __shared__ int s_meta[20];
    {
        const float* orow = obs + (long)b * OBS;
        #pragma unroll
        for (int k = 0; k < 4; ++k) {
            int i = t + k * 64;
            if (i < 210) {
                int c = i / 42, rem = i - 42 * c, r = rem / 6, col = rem - 6 * r;
                sb[S_V + c * 56 + r * 8 + col] = orow[i];
            }
        }
        #pragma unroll
        for (int k = 0; k < 8; ++k) {
            int i = 210 + t + k * 64;
            if (i < OBS) sb[S_OBS + i] = orow[i];
        }
    }
    __syncthreads();
    if (t < 20) {
        const float* nb = &sb[S_OBS + 242 + t * 22];
        int id = (int)nb[0], js = -1;
        #pragma unroll
        for (int j = 0; j < ACTN; ++j) {
            float av = nb[1 + j];
            js = (av != 0.f && js < 0) ? j : js;
        }
        int mode = (id < -1) ? 0 : ((id >= 0 && js < 0) ? 1 : 2);
        s_meta[t] = ((id + 2) << 8) | (mode << 5) | (js + 1);
    }
    {
        const int oc = t & 31, s = t >> 5;
        float acc[12];
        #pragma unroll
        for (int i = 0; i < 12; ++i) acc[i] = 0.f;
        #pragma unroll
        for (int c = 0; c < 5; ++c) {
            float wv[9];
            #pragma unroll
            for (int k = 0; k < 9; ++k) wv[k] = c1w[oc * 45 + c * 9 + k];
            #pragma unroll
            for (int rr = 0; rr < 5; ++rr) {
                const float* rowp = &sb[S_V + c * 56 + (2 * s + rr) * 8];
                float4 v0 = *(const float4*)rowp;
                float2 v1 = *(const float2*)(rowp + 4);
                float c0 = v0.x, c1 = v0.y, c2 = v0.z, c3 = v0.w, c4 = v1.x, c5 = v1.y;
                #pragma unroll
                for (int kh = 0; kh < 3; ++kh) {
                    int ohl = rr - kh;
                    if (ohl < 0 || ohl > 2) continue;
                    acc[ohl*4+0] = fmaf(c0, wv[kh*3+0], acc[ohl*4+0]);
                    acc[ohl*4+0] = fmaf(c1, wv[kh*3+1], acc[ohl*4+0]);
                    acc[ohl*4+0] = fmaf(c2, wv[kh*3+2], acc[ohl*4+0]);
                    acc[ohl*4+1] = fmaf(c1, wv[kh*3+0], acc[ohl*4+1]);
                    acc[ohl*4+1] = fmaf(c2, wv[kh*3+1], acc[ohl*4+1]);
                    acc[ohl*4+1] = fmaf(c3, wv[kh*3+2], acc[ohl*4+1]);
                    acc[ohl*4+2] = fmaf(c2, wv[kh*3+0], acc[ohl*4+2]);
                    acc[ohl*4+2] = fmaf(c3, wv[kh*3+1], acc[ohl*4+2]);
                    acc[ohl*4+2] = fmaf(c4, wv[kh*3+2], acc[ohl*4+2]);
                    acc[ohl*4+3] = fmaf(c3, wv[kh*3+0], acc[ohl*4+3]);
                    acc[ohl*4+3] = fmaf(c4, wv[kh*3+1], acc[ohl*4+3]);
                    acc[ohl*4+3] = fmaf(c5, wv[kh*3+2], acc[ohl*4+3]);
                }
            }
        }
        float bias = c1b[oc];
        #pragma unroll
        for (int ohl = 0; ohl < 3; ++ohl) {
            int oh = 2 * s + ohl;
            float4 o4 = make_float4(fmaxf(acc[ohl*4+0] + bias, 0.f), fmaxf(acc[ohl*4+1] + bias, 0.f),
                                    fmaxf(acc[ohl*4+2] + bias, 0.f), fmaxf(acc[ohl*4+3] + bias, 0.f));
            *(float4*)&sb[S_C1 + oc * 20 + oh * 4] = o4;
        }
    }
    __syncthreads();
    {
        const int oc = t & 31, half = t >> 5;
        float a0=0,a1=0,a2=0,a3=0,a4=0,a5=0;
        #pragma unroll 4
        for (int icc = 0; icc < 16; ++icc) {
            const int ic = half * 16 + icc;
            const float4* rp = (const float4*)&sb[S_C1 + ic * 20];
            float4 r0 = rp[0], r1 = rp[1], r2 = rp[2], r3 = rp[3], r4 = rp[4];
            float wv[9];
            #pragma unroll
            for (int k = 0; k < 9; ++k) wv[k] = c2w[oc * 288 + ic * 9 + k];
            #pragma unroll
            for (int kh = 0; kh < 3; ++kh) {
                float4 ra = (kh == 0) ? r0 : (kh == 1) ? r1 : r2;
                float4 rb = (kh == 0) ? r1 : (kh == 1) ? r2 : r3;
                float4 rc = (kh == 0) ? r2 : (kh == 1) ? r3 : r4;
                #pragma unroll
                for (int kw = 0; kw < 3; ++kw) {
                    float ww = wv[kh * 3 + kw];
                    a0 = fmaf(comp4(ra, kw),     ww, a0);
                    a1 = fmaf(comp4(ra, kw + 1), ww, a1);
                    a2 = fmaf(comp4(rb, kw),     ww, a2);
                    a3 = fmaf(comp4(rb, kw + 1), ww, a3);
                    a4 = fmaf(comp4(rc, kw),     ww, a4);
                    a5 = fmaf(comp4(rc, kw + 1), ww, a5);
                }
            }
        }
        float* pp = &sb[S_PART + (half * 32 + oc) * 6];
        pp[0]=a0; pp[1]=a1; pp[2]=a2; pp[3]=a3; pp[4]=a4; pp[5]=a5;
    }
    __syncthreads();
    if (t < 32) {
        float bias = c2b[t];
        #pragma unroll
        for (int p = 0; p < 6; ++p)
            sb[S_C2 + t * 6 + p] = fmaxf(sb[S_PART + t * 6 + p] + sb[S_PART + (32 + t) * 6 + p] + bias, 0.f);
    }
    __syncthreads();
    {
        float a0 = f1b[t], a1 = 0.f;
        const float4* xp = (const float4*)&sb[S_C2];
        #pragma unroll 4
        for (int kq = 0; kq < 48; ++kq) {
            float4 x = xp[kq];
            a0 = fmaf(x.x, f1w[(4*kq+0)*64+t], a0);
            a1 = fmaf(x.y, f1w[(4*kq+1)*64+t], a1);
            a0 = fmaf(x.z, f1w[(4*kq+2)*64+t], a0);
            a1 = fmaf(x.w, f1w[(4*kq+3)*64+t], a1);
        }
        sb[S_X + t] = fmaxf(a0 + a1, 0.f);
    }
    __syncthreads();
    float base_t;
    {
        float a0 = f2b[t], a1 = 0.f;
        const float4* xp = (const float4*)&sb[S_X];
        #pragma unroll 4
        for (int kq = 0; kq < 16; ++kq) {
            float4 x = xp[kq];
            a0 = fmaf(x.x, f2w[(4*kq+0)*64+t], a0);
            a1 = fmaf(x.y, f2w[(4*kq+1)*64+t], a1);
            a0 = fmaf(x.z, f2w[(4*kq+2)*64+t], a0);
            a1 = fmaf(x.w, f2w[(4*kq+3)*64+t], a1);
        }
        const float2* fp = (const float2*)&sb[S_OBS + 210];
        #pragma unroll 4
        for (int i2 = 0; i2 < 16; ++i2) {
            float2 v = fp[i2];
            a0 = fmaf(v.x, f2w[(64 + i2*2+0)*64+t], a0);
            a1 = fmaf(v.y, f2w[(64 + i2*2+1)*64+t], a1);
        }
        base_t = a0 + a1;
    }
    const float* W2id = f2w + 96 * 64;
    const float* W2act = f2w + 116 * 64;
    float hacc = 0.f, cnt = 0.f;
    for (int a = 0; a < 20; ++a) {
        int m = s_meta[a];
        int mode = (m >> 5) & 3;
        if (mode == 0) continue;
        int id = (m >> 8) - 2, js = (m & 31) - 1;
        float u = base_t + ((id >= 0) ? W2id[id * 64 + t] : 0.f);
        if (mode == 1) {
            float h0=0,h1=0,h2=0;
            #pragma unroll
            for (int j = 0; j < ACTN; j += 3) {
                h0 += fmaxf(u + W2act[(j    )*64+t], 0.f);
                h1 += fmaxf(u + W2act[(j + 1)*64+t], 0.f);
                h2 += fmaxf(u + W2act[(j + 2)*64+t], 0.f);
            }
            hacc += (h0 + h1) + h2; cnt += 21.f;
        } else {
            float ar = (js >= 0) ? W2act[js * 64 + t] : 0.f;
            hacc += fmaxf(u + ar, 0.f); cnt += 1.f;
        }
    }
    sb[S_H + t] = hacc;
    __syncthreads();
    if (t < ACTN) {
        float q0 = cnt * f3b[t], q1 = 0.f;
        const float4* hp = (const float4*)&sb[S_H];
        #pragma unroll 4
        for (int h4 = 0; h4 < 16; ++h4) {
            float4 v = hp[h4];
            q0 = fmaf(v.x, f3w[(h4*4+0)*21+t], q0);
            q1 = fmaf(v.y, f3w[(h4*4+1)*21+t], q1);
            q0 = fmaf(v.z, f3w[(h4*4+2)*21+t], q0);
            q1 = fmaf(v.w, f3w[(h4*4+3)*21+t], q1);
        }
        out[b * 21 + t] = q0 + q1;
    }
}

extern "C" void kernel_launch(void* const* d_in, const int* in_sizes, int n_in,
                              void* d_out, int out_size, void* d_ws, size_t ws_size,
                              hipStream_t stream) {
    const float* obs = (const float*)d_in[0];
    const float* c1w = (const float*)d_in[1];
    const float* c1b = (const float*)d_in[2];
    const float* c2w = (const float*)d_in[3];
    const float* c2b = (const float*)d_in[4];
    const float* f1w = (const float*)d_in[5];
    const float* f1b = (const float*)d_in[6];
    const float* f2w = (const float*)d_in[7];
    const float* f2b = (const float*)d_in[8];
    const float* f3w = (const float*)d_in[9];
    const float* f3b = (const float*)d_in[10];
    float* o = (float*)d_out;
    const int B = in_sizes[0] / OBS;

    if (ws_size >= (size_t)WS_TOTU * 2 && (B % MB) == 0) {
        unsigned short* wsu = (unsigned short*)d_ws;
        repack_b<<<(WS_TOTU + 255) / 256, 256, 0, stream>>>(c1w, c2w, f1w, wsu);
        mfma_k<<<B / MB, 512, 0, stream>>>(obs, c1b, c2b, f1b, f2w, f2b, f3w, f3b, wsu, o);
    } else {
        fallback_k<<<B, 64, 0, stream>>>(obs, c1w, c1b, c2w, c2b, f1w, f1b,
                                         f2w, f2b, f3w, f3b, o);
    }
}